// Round 10
// baseline (274.263 us; speedup 1.0000x reference)
//
#include <hip/hip_runtime.h>
#include <hip/hip_bf16.h>

// GatingNetwork: B=16384 rows, D=4096, H=OUT=7.
// R10: reg-hold burst WITHOUT LDS. R9's 57 KB LDS weight cache capped
// residency at ~1 block/CU (measured 20% occupancy); but the packed bf16
// weight buffer is only 57 KB TOTAL -> permanently L2-resident on every XCD.
// So: read weights straight from global (coalesced uint4, L2 ~200cy), no
// LDS, no __syncthreads. Each wave bursts all 32 f1/f2 float4 loads into
// registers (sched_barrier fence), gate-FMAs against streamed L2 weights,
// 49-op packed wave reduction, combine from registers (zero re-read).
// VGPR ~108 -> 4 waves/SIMD = 16 waves/CU, 2x R9 residency.

constexpr int Dk  = 4096;
constexpr int Hk  = 7;
constexpr int NPAIR = Dk / 512;                  // 8 pair-iters (512 floats)
constexpr int NWE   = Hk * NPAIR * 64;           // 3584 uint4 weight entries
constexpr int WPK_WORDS = NWE * 4;               // 14336 u32 words (57344 B)
constexpr size_t WS_NEEDED = (size_t)WPK_WORDS * 4 + 64;

constexpr int NTH = 512;
constexpr int ROWS_PER_BLOCK = 8;                // one row per wave

// gc floats at word offset WPK_WORDS: b1[7], s_j[7], sum(b2) at [14].
__global__ void gating_prep(const float* __restrict__ W1,
                            const float* __restrict__ b1,
                            const float* __restrict__ W2,
                            const float* __restrict__ b2,
                            unsigned int* __restrict__ wsw)
{
    const int t = blockIdx.x * blockDim.x + threadIdx.x;   // one thread/uint4
    if (t < NWE) {
        const int j    = t / (NPAIR * 64);
        const int kk   = (t / 64) % NPAIR;
        const int lane = t & 63;
        const int vi0  = (2 * kk) * 64 + lane;             // float4 idx, iter A
        unsigned int w[4];
        #pragma unroll
        for (int h = 0; h < 2; ++h) {                      // iter A / iter B
            const int vi = vi0 + h * 64;
            #pragma unroll
            for (int p = 0; p < 2; ++p) {                  // element pair
                const int d0 = 4 * vi + 2 * p;
                const unsigned int lo = (unsigned int)__bfloat16_as_ushort(
                    __float2bfloat16(W1[(long long)d0 * Hk + j]));
                const unsigned int hi = (unsigned int)__bfloat16_as_ushort(
                    __float2bfloat16(W1[(long long)(d0 + 1) * Hk + j]));
                w[h * 2 + p] = lo | (hi << 16);
            }
        }
        reinterpret_cast<uint4*>(wsw)[t] = make_uint4(w[0], w[1], w[2], w[3]);
    }
    if (blockIdx.x == 0 && threadIdx.x == 0) {
        float* c = reinterpret_cast<float*>(wsw) + WPK_WORDS;
        #pragma unroll
        for (int j = 0; j < Hk; ++j) {
            c[j] = b1[j];
            float s = 0.f;
            #pragma unroll
            for (int k = 0; k < Hk; ++k) s += W2[j * Hk + k];
            c[Hk + j] = s;
        }
        float sb2 = 0.f;
        #pragma unroll
        for (int k = 0; k < Hk; ++k) sb2 += b2[k];
        c[14] = sb2;
    }
}

__device__ __forceinline__ float bf_lo(unsigned int u) {
    return __uint_as_float(u << 16);
}
__device__ __forceinline__ float bf_hi(unsigned int u) {
    return __uint_as_float(u & 0xFFFF0000u);
}

__global__ __launch_bounds__(NTH, 2)
void gating_wave(const float* __restrict__ f1,
                 const float* __restrict__ f2,
                 const uint4* __restrict__ wpk,   // [7][8][64] in ws (57 KB, L2)
                 const float* __restrict__ gc,    // b1[7], s[7], sb2
                 float* __restrict__ out,
                 int rows)
{
    const int wid  = threadIdx.x >> 6;
    const int lane = threadIdx.x & 63;
    const int row  = blockIdx.x * ROWS_PER_BLOCK + wid;
    if (row >= rows) return;

    const long long base = (long long)row * Dk;
    const float4* __restrict__ f1v = reinterpret_cast<const float4*>(f1 + base);
    const float4* __restrict__ f2v = reinterpret_cast<const float4*>(f2 + base);

    // ---- Issue ALL 32 feature loads back-to-back (32 KB in flight) ----
    float4 a[16], b[16];
    #pragma unroll
    for (int k = 0; k < 16; ++k) {
        const int vi = k * 64 + lane;
        a[k] = f1v[vi];
        b[k] = f2v[vi];
    }
    // Fence: loads stay batched; results stay live for the register combine.
    __builtin_amdgcn_sched_barrier(0);

    float acc1[Hk], acc2[Hk];
    #pragma unroll
    for (int j = 0; j < Hk; ++j) { acc1[j] = 0.f; acc2[j] = 0.f; }

    // ---- Gate FMAs from registers + L2-resident packed weights ----
    #pragma unroll
    for (int kk = 0; kk < NPAIR; ++kk) {
        const float4 xa0 = a[2 * kk],     xb0 = b[2 * kk];
        const float4 xa1 = a[2 * kk + 1], xb1 = b[2 * kk + 1];
        #pragma unroll
        for (int j = 0; j < Hk; ++j) {
            const uint4 u = wpk[(j * NPAIR + kk) * 64 + lane];  // coalesced L2
            const float w0 = bf_lo(u.x), w1 = bf_hi(u.x);
            const float w2 = bf_lo(u.y), w3 = bf_hi(u.y);
            const float w4 = bf_lo(u.z), w5 = bf_hi(u.z);
            const float w6 = bf_lo(u.w), w7 = bf_hi(u.w);
            acc1[j] = fmaf(xa0.x, w0, fmaf(xa0.y, w1,
                      fmaf(xa0.z, w2, fmaf(xa0.w, w3, acc1[j]))));
            acc1[j] = fmaf(xa1.x, w4, fmaf(xa1.y, w5,
                      fmaf(xa1.z, w6, fmaf(xa1.w, w7, acc1[j]))));
            acc2[j] = fmaf(xb0.x, w0, fmaf(xb0.y, w1,
                      fmaf(xb0.z, w2, fmaf(xb0.w, w3, acc2[j]))));
            acc2[j] = fmaf(xb1.x, w4, fmaf(xb1.y, w5,
                      fmaf(xb1.z, w6, fmaf(xb1.w, w7, acc2[j]))));
        }
    }

    // ---- packed wave reduction: 14 + 35 cross-lane ops ----
    #pragma unroll
    for (int j = 0; j < Hk; ++j) {
        acc1[j] += __shfl_xor(acc1[j], 32);
        acc2[j] += __shfl_xor(acc2[j], 32);
    }
    float val[Hk];
    #pragma unroll
    for (int j = 0; j < Hk; ++j)
        val[j] = (lane < 32) ? acc1[j] : acc2[j];
    #pragma unroll
    for (int off = 16; off >= 1; off >>= 1) {
        #pragma unroll
        for (int j = 0; j < Hk; ++j)
            val[j] += __shfl_xor(val[j], off);
    }
    // lanes 0-31: expert-1 totals; lanes 32-63: expert-2 totals.

    float logit = 0.f;
    #pragma unroll
    for (int j = 0; j < Hk; ++j)
        logit = fmaf(fmaxf(val[j] + gc[j], 0.f), gc[Hk + j], logit);
    logit = (logit + gc[14]) * (1.f / 7.f);

    const float other = __shfl_xor(logit, 32);
    const float delta = (lane < 32) ? (other - logit) : (logit - other);
    const float a0 = 1.f / (1.f + expf(delta));   // weight of expert 1
    const float a1 = 1.f - a0;

    // ---- combine FROM REGISTERS (zero re-read) ----
    float4* __restrict__ ov = reinterpret_cast<float4*>(out + base);
    #pragma unroll
    for (int k = 0; k < 16; ++k) {
        const int vi = k * 64 + lane;
        float4 o;
        o.x = fmaf(a0, a[k].x, a1 * b[k].x);
        o.y = fmaf(a0, a[k].y, a1 * b[k].y);
        o.z = fmaf(a0, a[k].z, a1 * b[k].z);
        o.w = fmaf(a0, a[k].w, a1 * b[k].w);
        ov[vi] = o;
    }
}

// Fallback (ws too small): direct-W1 f32 path (known correct, from R1).
__global__ __launch_bounds__(256, 4)
void gating_fused_direct(const float* __restrict__ f1,
                         const float* __restrict__ f2,
                         const float* __restrict__ W1,
                         const float* __restrict__ b1,
                         const float* __restrict__ W2,
                         const float* __restrict__ b2,
                         float* __restrict__ out)
{
    constexpr int VPT = 4;
    const int row = blockIdx.x;
    const int t   = threadIdx.x;
    const long long base = (long long)row * Dk;

    const float4* f1v = reinterpret_cast<const float4*>(f1 + base);
    const float4* f2v = reinterpret_cast<const float4*>(f2 + base);

    float4 r1[VPT], r2[VPT];
    float acc1[Hk], acc2[Hk];
    #pragma unroll
    for (int j = 0; j < Hk; ++j) { acc1[j] = 0.f; acc2[j] = 0.f; }

    #pragma unroll
    for (int k = 0; k < VPT; ++k) {
        const int vi = k * 256 + t;
        r1[k] = f1v[vi];
        r2[k] = f2v[vi];
        const float4* wv = reinterpret_cast<const float4*>(W1 + (long long)vi * 28);
        float4 w4[7];
        #pragma unroll
        for (int q = 0; q < 7; ++q) w4[q] = wv[q];
        const float* ws = reinterpret_cast<const float*>(w4);
        const float* x1 = reinterpret_cast<const float*>(&r1[k]);
        const float* x2 = reinterpret_cast<const float*>(&r2[k]);
        #pragma unroll
        for (int r = 0; r < 4; ++r)
            #pragma unroll
            for (int j = 0; j < Hk; ++j) {
                acc1[j] = fmaf(x1[r], ws[r * 7 + j], acc1[j]);
                acc2[j] = fmaf(x2[r], ws[r * 7 + j], acc2[j]);
            }
    }
    #pragma unroll
    for (int j = 0; j < Hk; ++j)
        #pragma unroll
        for (int off = 32; off >= 1; off >>= 1) {
            acc1[j] += __shfl_down(acc1[j], off);
            acc2[j] += __shfl_down(acc2[j], off);
        }

    __shared__ float red[4][2 * Hk];
    __shared__ float alpha[2];
    const int wave = t >> 6;
    const int lane = t & 63;
    if (lane == 0)
        #pragma unroll
        for (int j = 0; j < Hk; ++j) {
            red[wave][j]      = acc1[j];
            red[wave][Hk + j] = acc2[j];
        }
    __syncthreads();

    if (t == 0) {
        float l1 = 0.f, l2 = 0.f;
        #pragma unroll
        for (int j = 0; j < Hk; ++j) {
            float h1 = red[0][j] + red[1][j] + red[2][j] + red[3][j] + b1[j];
            float h2 = red[0][Hk + j] + red[1][Hk + j] + red[2][Hk + j]
                     + red[3][Hk + j] + b1[j];
            float s = 0.f;
            #pragma unroll
            for (int k2 = 0; k2 < Hk; ++k2) s += W2[j * Hk + k2];
            l1 = fmaf(fmaxf(h1, 0.f), s, l1);
            l2 = fmaf(fmaxf(h2, 0.f), s, l2);
        }
        float sb2 = 0.f;
        #pragma unroll
        for (int k2 = 0; k2 < Hk; ++k2) sb2 += b2[k2];
        l1 = (l1 + sb2) * (1.f / 7.f);
        l2 = (l2 + sb2) * (1.f / 7.f);
        const float a0 = 1.f / (1.f + expf(l2 - l1));
        alpha[0] = a0;
        alpha[1] = 1.f - a0;
    }
    __syncthreads();

    const float a0 = alpha[0];
    const float a1 = alpha[1];
    float4* ov = reinterpret_cast<float4*>(out + base);
    #pragma unroll
    for (int k = 0; k < VPT; ++k) {
        const int vi = k * 256 + t;
        float4 o;
        o.x = a0 * r1[k].x + a1 * r2[k].x;
        o.y = a0 * r1[k].y + a1 * r2[k].y;
        o.z = a0 * r1[k].z + a1 * r2[k].z;
        o.w = a0 * r1[k].w + a1 * r2[k].w;
        ov[vi] = o;
    }
}

extern "C" void kernel_launch(void* const* d_in, const int* in_sizes, int n_in,
                              void* d_out, int out_size, void* d_ws, size_t ws_size,
                              hipStream_t stream) {
    const float* f1 = (const float*)d_in[0];
    const float* f2 = (const float*)d_in[1];
    const float* W1 = (const float*)d_in[2];
    const float* b1 = (const float*)d_in[3];
    const float* W2 = (const float*)d_in[4];
    const float* b2 = (const float*)d_in[5];
    float* out = (float*)d_out;
    const int rows = in_sizes[0] / Dk;   // 16384

    if (ws_size >= WS_NEEDED) {
        unsigned int* wsw = (unsigned int*)d_ws;
        gating_prep<<<(NWE + 255) / 256, 256, 0, stream>>>(W1, b1, W2, b2, wsw);
        const int blocks = (rows + ROWS_PER_BLOCK - 1) / ROWS_PER_BLOCK;
        gating_wave<<<blocks, NTH, 0, stream>>>(
            f1, f2, reinterpret_cast<const uint4*>(wsw),
            reinterpret_cast<const float*>(wsw) + WPK_WORDS, out, rows);
    } else {
        gating_fused_direct<<<rows, 256, 0, stream>>>(f1, f2, W1, b1, W2, b2, out);
    }
}

// Round 11
// 164.288 us; speedup vs baseline: 1.6694x; 1.6694x over previous
//
#include <hip/hip_runtime.h>
#include <hip/hip_bf16.h>

// GatingNetwork: B=16384 rows, D=4096, H=OUT=7.
// R11: quarter-row reg-hold. R9 (full-row burst, 108 VGPR) capped at 4
// waves/SIMD; its ~8 waves/CU couldn't keep HBM fed (3.1 TB/s). R10 proved
// weights must stay in LDS. Here each wave owns 1024 elements (a[4]/b[4]
// burst = 32 VGPR), 4 waves per row; intra-wave packed reduction + tiny LDS
// exchange; alpha computed lane-uniformly by every thread; combine from
// registers. VGPR target <=64 via __launch_bounds__(1024,8) -> 8 waves/SIMD,
// 2 blocks/CU (LDS 58 KB) = 32 waves/CU, 4x R9's residency with the same
// per-wave burst ILP. Weights bf16-pair-packed in LDS (57 KB).

constexpr int Dk  = 4096;
constexpr int Hk  = 7;
constexpr int NPAIR = Dk / 512;                  // 8 pair-iters (512 floats)
constexpr int NWE   = Hk * NPAIR * 64;           // 3584 uint4 weight entries
constexpr int WPK_WORDS = NWE * 4;               // 14336 u32 words (57344 B)
constexpr size_t WS_NEEDED = (size_t)WPK_WORDS * 4 + 64;

constexpr int NTH = 1024;                        // 16 waves
constexpr int ROWS_PER_BLOCK = 4;                // 4 waves per row

// gc floats at word offset WPK_WORDS: b1[7], s_j[7], sum(b2) at [14].
__global__ void gating_prep(const float* __restrict__ W1,
                            const float* __restrict__ b1,
                            const float* __restrict__ W2,
                            const float* __restrict__ b2,
                            unsigned int* __restrict__ wsw)
{
    const int t = blockIdx.x * blockDim.x + threadIdx.x;   // one thread/uint4
    if (t < NWE) {
        const int j    = t / (NPAIR * 64);
        const int kk   = (t / 64) % NPAIR;
        const int lane = t & 63;
        const int vi0  = (2 * kk) * 64 + lane;             // float4 idx, iter A
        unsigned int w[4];
        #pragma unroll
        for (int h = 0; h < 2; ++h) {                      // iter A / iter B
            const int vi = vi0 + h * 64;
            #pragma unroll
            for (int p = 0; p < 2; ++p) {                  // element pair
                const int d0 = 4 * vi + 2 * p;
                const unsigned int lo = (unsigned int)__bfloat16_as_ushort(
                    __float2bfloat16(W1[(long long)d0 * Hk + j]));
                const unsigned int hi = (unsigned int)__bfloat16_as_ushort(
                    __float2bfloat16(W1[(long long)(d0 + 1) * Hk + j]));
                w[h * 2 + p] = lo | (hi << 16);
            }
        }
        reinterpret_cast<uint4*>(wsw)[t] = make_uint4(w[0], w[1], w[2], w[3]);
    }
    if (blockIdx.x == 0 && threadIdx.x == 0) {
        float* c = reinterpret_cast<float*>(wsw) + WPK_WORDS;
        #pragma unroll
        for (int j = 0; j < Hk; ++j) {
            c[j] = b1[j];
            float s = 0.f;
            #pragma unroll
            for (int k = 0; k < Hk; ++k) s += W2[j * Hk + k];
            c[Hk + j] = s;
        }
        float sb2 = 0.f;
        #pragma unroll
        for (int k = 0; k < Hk; ++k) sb2 += b2[k];
        c[14] = sb2;
    }
}

__device__ __forceinline__ float bf_lo(unsigned int u) {
    return __uint_as_float(u << 16);
}
__device__ __forceinline__ float bf_hi(unsigned int u) {
    return __uint_as_float(u & 0xFFFF0000u);
}

__global__ __launch_bounds__(NTH, 8)
void gating_wave(const float* __restrict__ f1,
                 const float* __restrict__ f2,
                 const uint4* __restrict__ wpk,   // [7][8][64] in ws
                 const float* __restrict__ gc,    // b1[7], s[7], sb2
                 float* __restrict__ out,
                 int rows)
{
    __shared__ uint4 wl[NWE];                          // 57344 B
    __shared__ float red[ROWS_PER_BLOCK][2][Hk][4];    // 896 B

    // Cooperative weight stage: 3584 entries / 1024 threads.
    for (int e = threadIdx.x; e < NWE; e += NTH)
        wl[e] = wpk[e];
    __syncthreads();

    const int wid  = threadIdx.x >> 6;
    const int lane = threadIdx.x & 63;
    const int lrow = wid >> 2;                   // row within block
    const int q    = wid & 3;                    // quarter of the row
    int row = blockIdx.x * ROWS_PER_BLOCK + lrow;
    if (row >= rows) row = rows - 1;             // clamp (no early return: barriers)

    const long long base = (long long)row * Dk;
    const float4* __restrict__ f1v = reinterpret_cast<const float4*>(f1 + base);
    const float4* __restrict__ f2v = reinterpret_cast<const float4*>(f2 + base);

    // ---- Burst this quarter's 8 loads (8 KB in flight) ----
    float4 a[4], b[4];
    #pragma unroll
    for (int i = 0; i < 4; ++i) {
        const int vi = (4 * q + i) * 64 + lane;
        a[i] = f1v[vi];
        b[i] = f2v[vi];
    }
    __builtin_amdgcn_sched_barrier(0);

    float acc1[Hk], acc2[Hk];
    #pragma unroll
    for (int j = 0; j < Hk; ++j) { acc1[j] = 0.f; acc2[j] = 0.f; }

    // ---- Gate FMAs from registers + LDS weights (this quarter: kk=2q,2q+1) ----
    #pragma unroll
    for (int kk2 = 0; kk2 < 2; ++kk2) {
        const int kk = 2 * q + kk2;
        const float4 xa0 = a[2 * kk2],     xb0 = b[2 * kk2];
        const float4 xa1 = a[2 * kk2 + 1], xb1 = b[2 * kk2 + 1];
        #pragma unroll
        for (int j = 0; j < Hk; ++j) {
            const uint4 u = wl[(j * NPAIR + kk) * 64 + lane];   // ds_read_b128
            const float w0 = bf_lo(u.x), w1 = bf_hi(u.x);
            const float w2 = bf_lo(u.y), w3 = bf_hi(u.y);
            const float w4 = bf_lo(u.z), w5 = bf_hi(u.z);
            const float w6 = bf_lo(u.w), w7 = bf_hi(u.w);
            acc1[j] = fmaf(xa0.x, w0, fmaf(xa0.y, w1,
                      fmaf(xa0.z, w2, fmaf(xa0.w, w3, acc1[j]))));
            acc1[j] = fmaf(xa1.x, w4, fmaf(xa1.y, w5,
                      fmaf(xa1.z, w6, fmaf(xa1.w, w7, acc1[j]))));
            acc2[j] = fmaf(xb0.x, w0, fmaf(xb0.y, w1,
                      fmaf(xb0.z, w2, fmaf(xb0.w, w3, acc2[j]))));
            acc2[j] = fmaf(xb1.x, w4, fmaf(xb1.y, w5,
                      fmaf(xb1.z, w6, fmaf(xb1.w, w7, acc2[j]))));
        }
    }

    // ---- packed intra-wave reduction: 14 + 35 cross-lane ops ----
    #pragma unroll
    for (int j = 0; j < Hk; ++j) {
        acc1[j] += __shfl_xor(acc1[j], 32);
        acc2[j] += __shfl_xor(acc2[j], 32);
    }
    float val[Hk];
    #pragma unroll
    for (int j = 0; j < Hk; ++j)
        val[j] = (lane < 32) ? acc1[j] : acc2[j];
    #pragma unroll
    for (int off = 16; off >= 1; off >>= 1) {
        #pragma unroll
        for (int j = 0; j < Hk; ++j)
            val[j] += __shfl_xor(val[j], off);
    }
    // lane 0: expert-1 partials for this quarter; lane 32: expert-2 partials.

    if ((lane & 31) == 0) {
        const int e = lane >> 5;
        #pragma unroll
        for (int j = 0; j < Hk; ++j)
            red[lrow][e][j][q] = val[j];
    }
    __syncthreads();

    // ---- alpha: every lane redundantly (LDS broadcast reads, no shuffles) ----
    float l1 = 0.f, l2 = 0.f;
    #pragma unroll
    for (int j = 0; j < Hk; ++j) {
        const float4 r1q = *reinterpret_cast<const float4*>(&red[lrow][0][j][0]);
        const float4 r2q = *reinterpret_cast<const float4*>(&red[lrow][1][j][0]);
        const float h1 = r1q.x + r1q.y + r1q.z + r1q.w + gc[j];
        const float h2 = r2q.x + r2q.y + r2q.z + r2q.w + gc[j];
        l1 = fmaf(fmaxf(h1, 0.f), gc[Hk + j], l1);
        l2 = fmaf(fmaxf(h2, 0.f), gc[Hk + j], l2);
    }
    const float delta = (l2 - l1) * (1.f / 7.f);      // sb2 cancels in softmax
    const float a0 = 1.f / (1.f + expf(delta));       // weight of expert 1
    const float a1 = 1.f - a0;

    // ---- combine FROM REGISTERS (zero re-read) ----
    float4* __restrict__ ov = reinterpret_cast<float4*>(out + base);
    #pragma unroll
    for (int i = 0; i < 4; ++i) {
        const int vi = (4 * q + i) * 64 + lane;
        float4 o;
        o.x = fmaf(a0, a[i].x, a1 * b[i].x);
        o.y = fmaf(a0, a[i].y, a1 * b[i].y);
        o.z = fmaf(a0, a[i].z, a1 * b[i].z);
        o.w = fmaf(a0, a[i].w, a1 * b[i].w);
        ov[vi] = o;
    }
}

// Fallback (ws too small): direct-W1 f32 path (known correct, from R1).
__global__ __launch_bounds__(256, 4)
void gating_fused_direct(const float* __restrict__ f1,
                         const float* __restrict__ f2,
                         const float* __restrict__ W1,
                         const float* __restrict__ b1,
                         const float* __restrict__ W2,
                         const float* __restrict__ b2,
                         float* __restrict__ out)
{
    constexpr int VPT = 4;
    const int row = blockIdx.x;
    const int t   = threadIdx.x;
    const long long base = (long long)row * Dk;

    const float4* f1v = reinterpret_cast<const float4*>(f1 + base);
    const float4* f2v = reinterpret_cast<const float4*>(f2 + base);

    float4 r1[VPT], r2[VPT];
    float acc1[Hk], acc2[Hk];
    #pragma unroll
    for (int j = 0; j < Hk; ++j) { acc1[j] = 0.f; acc2[j] = 0.f; }

    #pragma unroll
    for (int k = 0; k < VPT; ++k) {
        const int vi = k * 256 + t;
        r1[k] = f1v[vi];
        r2[k] = f2v[vi];
        const float4* wv = reinterpret_cast<const float4*>(W1 + (long long)vi * 28);
        float4 w4[7];
        #pragma unroll
        for (int q = 0; q < 7; ++q) w4[q] = wv[q];
        const float* ws = reinterpret_cast<const float*>(w4);
        const float* x1 = reinterpret_cast<const float*>(&r1[k]);
        const float* x2 = reinterpret_cast<const float*>(&r2[k]);
        #pragma unroll
        for (int r = 0; r < 4; ++r)
            #pragma unroll
            for (int j = 0; j < Hk; ++j) {
                acc1[j] = fmaf(x1[r], ws[r * 7 + j], acc1[j]);
                acc2[j] = fmaf(x2[r], ws[r * 7 + j], acc2[j]);
            }
    }
    #pragma unroll
    for (int j = 0; j < Hk; ++j)
        #pragma unroll
        for (int off = 32; off >= 1; off >>= 1) {
            acc1[j] += __shfl_down(acc1[j], off);
            acc2[j] += __shfl_down(acc2[j], off);
        }

    __shared__ float red[4][2 * Hk];
    __shared__ float alpha[2];
    const int wave = t >> 6;
    const int lane = t & 63;
    if (lane == 0)
        #pragma unroll
        for (int j = 0; j < Hk; ++j) {
            red[wave][j]      = acc1[j];
            red[wave][Hk + j] = acc2[j];
        }
    __syncthreads();

    if (t == 0) {
        float l1 = 0.f, l2 = 0.f;
        #pragma unroll
        for (int j = 0; j < Hk; ++j) {
            float h1 = red[0][j] + red[1][j] + red[2][j] + red[3][j] + b1[j];
            float h2 = red[0][Hk + j] + red[1][Hk + j] + red[2][Hk + j]
                     + red[3][Hk + j] + b1[j];
            float s = 0.f;
            #pragma unroll
            for (int k2 = 0; k2 < Hk; ++k2) s += W2[j * Hk + k2];
            l1 = fmaf(fmaxf(h1, 0.f), s, l1);
            l2 = fmaf(fmaxf(h2, 0.f), s, l2);
        }
        float sb2 = 0.f;
        #pragma unroll
        for (int k2 = 0; k2 < Hk; ++k2) sb2 += b2[k2];
        l1 = (l1 + sb2) * (1.f / 7.f);
        l2 = (l2 + sb2) * (1.f / 7.f);
        const float a0 = 1.f / (1.f + expf(l2 - l1));
        alpha[0] = a0;
        alpha[1] = 1.f - a0;
    }
    __syncthreads();

    const float a0 = alpha[0];
    const float a1 = alpha[1];
    float4* ov = reinterpret_cast<float4*>(out + base);
    #pragma unroll
    for (int k = 0; k < VPT; ++k) {
        const int vi = k * 256 + t;
        float4 o;
        o.x = a0 * r1[k].x + a1 * r2[k].x;
        o.y = a0 * r1[k].y + a1 * r2[k].y;
        o.z = a0 * r1[k].z + a1 * r2[k].z;
        o.w = a0 * r1[k].w + a1 * r2[k].w;
        ov[vi] = o;
    }
}

extern "C" void kernel_launch(void* const* d_in, const int* in_sizes, int n_in,
                              void* d_out, int out_size, void* d_ws, size_t ws_size,
                              hipStream_t stream) {
    const float* f1 = (const float*)d_in[0];
    const float* f2 = (const float*)d_in[1];
    const float* W1 = (const float*)d_in[2];
    const float* b1 = (const float*)d_in[3];
    const float* W2 = (const float*)d_in[4];
    const float* b2 = (const float*)d_in[5];
    float* out = (float*)d_out;
    const int rows = in_sizes[0] / Dk;   // 16384

    if (ws_size >= WS_NEEDED) {
        unsigned int* wsw = (unsigned int*)d_ws;
        gating_prep<<<(NWE + 255) / 256, 256, 0, stream>>>(W1, b1, W2, b2, wsw);
        const int blocks = (rows + ROWS_PER_BLOCK - 1) / ROWS_PER_BLOCK;
        gating_wave<<<blocks, NTH, 0, stream>>>(
            f1, f2, reinterpret_cast<const uint4*>(wsw),
            reinterpret_cast<const float*>(wsw) + WPK_WORDS, out, rows);
    } else {
        gating_fused_direct<<<rows, 256, 0, stream>>>(f1, f2, W1, b1, W2, b2, out);
    }
}